// Round 16
// baseline (776.281 us; speedup 1.0000x reference)
//
#include <hip/hip_runtime.h>
#include <math.h>

#define DI __device__ __forceinline__

typedef __attribute__((ext_vector_type(8))) short bf16x8;
typedef __attribute__((ext_vector_type(4))) float f32x4;

DI float silu_f(float v) { return v / (1.f + __expf(-v)); }
DI float4 ld4(const float* p) { return *reinterpret_cast<const float4*>(p); }
DI void st4(float* p, const float4& v) { *reinterpret_cast<float4*>(p) = v; }
DI unsigned short f2bf(float f) {
    unsigned u = __float_as_uint(f);
    unsigned r = (u + 0x7FFFu + ((u >> 16) & 1u)) >> 16;
    return (unsigned short)r;
}
DI float bf2f(unsigned short u) { return __uint_as_float(((unsigned)u) << 16); }

DI void gload_lds16(const unsigned short* g, unsigned short* l) {
    __builtin_amdgcn_global_load_lds(
        (const __attribute__((address_space(1))) void*)g,
        (__attribute__((address_space(3))) void*)l, 16, 0, 0);
}

// ---------------------------------------------------------------------------
// Weight pre-pack v2 (3x3): [Ci/32][Co/COG][9][COG][32]
// ---------------------------------------------------------------------------
__global__ void pack_w2_kernel(const float* __restrict__ w, unsigned short* __restrict__ pk,
                               int Ci, int Co, int COG) {
    int idx = blockIdx.x * 256 + threadIdx.x;
    int total = Ci * Co * 9;
    if (idx >= total) return;
    int cc = idx & 31;
    int t = idx >> 5;
    int col = t % COG; t /= COG;
    int dydx = t % 9;  t /= 9;
    int nCoG = Co / COG;
    int cog = t % nCoG;
    int ch = t / nCoG;
    int co = cog * COG + col;
    pk[idx] = f2bf(w[((size_t)co * Ci + (ch << 5) + cc) * 9 + dydx]);
}

// 1x1 weight pack: w [64][512] -> [16][64][32]
__global__ void pack_w1_kernel(const float* __restrict__ w, unsigned short* __restrict__ pk) {
    int idx = blockIdx.x * 256 + threadIdx.x;
    if (idx >= 32768) return;
    int cc = idx & 31;
    int col = (idx >> 5) & 63;
    int ch = idx >> 11;
    pk[idx] = f2bf(w[(size_t)col * 512 + (ch << 5) + cc]);
}

// ---------------------------------------------------------------------------
// Zero only the 1-px halo ring of a padded packed buffer [P][Hp][Wp][32]
// ---------------------------------------------------------------------------
__global__ void zero_halo_kernel(unsigned short* __restrict__ pk, int P, int Hp, int Wp) {
    int border = 2 * Wp + 2 * (Hp - 2);
    int idx = blockIdx.x * 256 + threadIdx.x;
    if (idx >= P * border) return;
    int i = idx % border;
    int p = idx / border;
    int y, x;
    if (i < Wp) { y = 0; x = i; }
    else if (i < 2 * Wp) { y = Hp - 1; x = i - Wp; }
    else if (i < 2 * Wp + (Hp - 2)) { y = i - 2 * Wp + 1; x = 0; }
    else { y = i - 2 * Wp - (Hp - 2) + 1; x = Wp - 1; }
    unsigned short* d = pk + (((size_t)p * Hp + y) * Wp + x) * 32;
    uint4 z = make_uint4(0, 0, 0, 0);
    *(uint4*)&d[0] = z; *(uint4*)&d[8] = z; *(uint4*)&d[16] = z; *(uint4*)&d[24] = z;
}

// ---------------------------------------------------------------------------
// Input pre-pack with zero halo: f32 NCHW -> bf16 [b][ci/32][H+2][W+2][32]
// ---------------------------------------------------------------------------
__global__ void pack_in_pad_kernel(const float* __restrict__ in, unsigned short* __restrict__ pk,
                                   int Ci, int H, int W, int total) {
    int idx = blockIdx.x * 256 + threadIdx.x;
    if (idx >= total) return;
    const int nCh = Ci >> 5;
    const int HW = H * W;
    int cg = idx & 3;
    int t = idx >> 2;
    int pix = t % HW; t /= HW;
    int ch = t % nCh;
    int b = t / nCh;
    int y = pix / W, x = pix % W;
    const float* src = in + ((size_t)b * Ci + (ch << 5) + (cg << 3)) * HW + pix;
    unsigned p[4];
#pragma unroll
    for (int j = 0; j < 4; ++j) {
        float v0 = src[(size_t)(2 * j) * HW];
        float v1 = src[(size_t)(2 * j + 1) * HW];
        p[j] = (unsigned)f2bf(v0) | ((unsigned)f2bf(v1) << 16);
    }
    size_t dst = (((size_t)b * nCh + ch) * (H + 2) + (y + 1)) * (W + 2) + (x + 1);
    *(uint4*)&pk[dst * 32 + (cg << 3)] = make_uint4(p[0], p[1], p[2], p[3]);
}

// ---------------------------------------------------------------------------
// MFMA implicit-GEMM 3x3 conv body (v3b structure, settled). Callable from
// standalone wrapper or a fat multi-conv dispatcher (lbid = logical block id,
// nwg = logical grid size for the XCD swizzle).
// ---------------------------------------------------------------------------
template <int TH, int TW, int BF, int WCO, int FUSE, int OUTPK, int OUTPAD>
DI void conv3x3_body(unsigned short* lin, int lbid, int nwg,
                     const unsigned short* __restrict__ pin,
                     const unsigned short* __restrict__ wpk,
                     float* __restrict__ out, unsigned short* __restrict__ outpk,
                     int B, int Ci, int Co, int H, int W,
                     const float* __restrict__ ctx, const float* __restrict__ xres) {
    static_assert(TH * TW == 4 * BF * 16, "tile px = 4 waves * BF frags * 16");
    constexpr int COG = WCO * 16;
    constexpr int TWH = TW + 2;
    constexpr int HP = (TH + 2) * TWH;
    constexpr int NG = HP * 4;
    constexpr int NIT = (NG + 255) / 256;
    static_assert(NG % 8 == 0, "granules divisible by 8");

    const int nTx = W / TW, nTy = H / TH, nCoG = Co / COG;
    const int Wp = W + 2, Hp = H + 2;
    int wg = (lbid & 7) * (nwg >> 3) + (lbid >> 3);
    const int cog = wg % nCoG; wg /= nCoG;
    const int tx = wg % nTx;   wg /= nTx;
    const int ty = wg % nTy;
    const int b = wg / nTy;
    const int ox = tx * TW, oy = ty * TH, co0 = cog * COG;

    const int tid = threadIdx.x;
    const int lane = tid & 63;
    const int l15 = lane & 15, g = lane >> 4;
    const int wpx = (tid >> 6) * (BF * 16);

    int rr[BF], cc_[BF];
#pragma unroll
    for (int bf = 0; bf < BF; ++bf) {
        int px = wpx + bf * 16 + l15;
        rr[bf] = px / TW;
        cc_[bf] = px % TW;
    }

    f32x4 acc[WCO][BF];
#pragma unroll
    for (int af = 0; af < WCO; ++af)
#pragma unroll
        for (int bf = 0; bf < BF; ++bf) acc[af][bf] = {};

    const int nCh = Ci >> 5;
    const size_t HWs = (size_t)H * W;
    const size_t HpWp = (size_t)Hp * Wp;

    for (int ch = 0; ch < nCh; ++ch) {
        {
            const unsigned short* srcb = pin + ((size_t)b * nCh + ch) * HpWp * 32;
#pragma unroll
            for (int it = 0; it < NIT; ++it) {
                int s = it * 256 + tid;
                if (s < NG) {
                    int e = s ^ ((s >> 3) & 7);
                    int hp = e >> 2, cgp = e & 3;
                    int hy = hp / TWH, hx = hp - hy * TWH;
                    gload_lds16(srcb + ((size_t)(oy + hy) * Wp + (ox + hx)) * 32 + (cgp << 3),
                                &lin[(s & ~63) << 3]);
                }
            }
        }
        __syncthreads();
        {
            const unsigned short* wbase =
                wpk + ((((size_t)ch * nCoG + cog) * 9) * COG + l15) * 32 + (g << 3);
#pragma unroll
            for (int dy = 0; dy < 3; ++dy) {
#pragma unroll
                for (int dx = 0; dx < 3; ++dx) {
                    const int dydx = dy * 3 + dx;
                    bf16x8 a[WCO];
#pragma unroll
                    for (int af = 0; af < WCO; ++af)
                        a[af] = *(const bf16x8*)(wbase + ((size_t)dydx * COG + af * 16) * 32);
                    bf16x8 bb[BF];
#pragma unroll
                    for (int bf = 0; bf < BF; ++bf) {
                        int pxh = (rr[bf] + dy) * TWH + cc_[bf] + dx;
                        int eg = (pxh << 2) | g;
                        int slot = eg ^ ((eg >> 3) & 7);
                        bb[bf] = *(const bf16x8*)&lin[slot << 3];
                    }
#pragma unroll
                    for (int af = 0; af < WCO; ++af)
#pragma unroll
                        for (int bf = 0; bf < BF; ++bf)
                            acc[af][bf] = __builtin_amdgcn_mfma_f32_16x16x32_bf16(
                                a[af], bb[bf], acc[af][bf], 0, 0, 0);
                }
            }
        }
        __syncthreads();
    }

    const int nChO = Co >> 5;
    const size_t opitch = OUTPAD ? (size_t)(H + 2) * (W + 2) : HWs;
#pragma unroll
    for (int af = 0; af < WCO; ++af) {
#pragma unroll
        for (int bf = 0; bf < BF; ++bf) {
            int px = wpx + bf * 16 + l15;
            int y = oy + px / TW, x = ox + px % TW;
            size_t pixg = (size_t)y * W + x;
            int coB = co0 + af * 16 + (g << 2);
            float vv[4];
#pragma unroll
            for (int r4 = 0; r4 < 4; ++r4) {
                float v = acc[af][bf][r4];
                if (FUSE == 1) v = silu_f(v);
                else if (FUSE == 2) {
                    size_t base = ((size_t)b * Co + coB + r4) * HWs + pixg;
                    v = xres[base] + ctx[base] * (1.f + tanhf(v));
                }
                vv[r4] = v;
            }
            if (OUTPK != 1) {
#pragma unroll
                for (int r4 = 0; r4 < 4; ++r4)
                    out[((size_t)b * Co + coB + r4) * HWs + pixg] = vv[r4];
            }
            if (OUTPK >= 1) {
                ushort4 s;
                s.x = f2bf(vv[0]); s.y = f2bf(vv[1]); s.z = f2bf(vv[2]); s.w = f2bf(vv[3]);
                size_t opix = OUTPAD ? ((size_t)(y + 1) * (W + 2) + (x + 1)) : pixg;
                *(ushort4*)&outpk[(((size_t)b * nChO + (coB >> 5)) * opitch + opix) * 32
                                  + (coB & 31)] = s;
            }
        }
    }
}

// Standalone wrapper (K7, K8)
template <int TH, int TW, int BF, int WCO, int FUSE, int OUTPK, int OUTPAD>
__global__ void __launch_bounds__(256)
conv3x3_mfma3(const unsigned short* __restrict__ pin, const unsigned short* __restrict__ wpk,
              float* __restrict__ out, unsigned short* __restrict__ outpk,
              int B, int Ci, int Co, int H, int W,
              const float* __restrict__ ctx, const float* __restrict__ xres) {
    constexpr int NG = ((TH + 2) * (TW + 2)) * 4;
    __shared__ __align__(16) unsigned short lin[NG * 8];
    conv3x3_body<TH, TW, BF, WCO, FUSE, OUTPK, OUTPAD>(
        lin, blockIdx.x, gridDim.x, pin, wpk, out, outpk, B, Ci, Co, H, W, ctx, xres);
}

// Fat dispatcher: blocks [0,1152) run K10 (p5 conv), [1152,1920) run K1 (p3).
__global__ void __launch_bounds__(256)
conv_k10k1(const unsigned short* __restrict__ p5_pk, const unsigned short* __restrict__ w8_pk,
           unsigned short* __restrict__ cp_pk,
           const unsigned short* __restrict__ p3_pk, const unsigned short* __restrict__ wred_pk,
           float* __restrict__ x_) {
    // max LDS of both bodies: K10 NG=18*18*4=1296 granules -> 20736 B
    __shared__ __align__(16) unsigned short lin[1296 * 8];
    if (blockIdx.x < 1152) {
        conv3x3_body<16, 16, 4, 4, 1, 1, 0>(
            lin, blockIdx.x, 1152, p5_pk, w8_pk, nullptr, cp_pk,
            8, 256, 256, 96, 96, nullptr, nullptr);
    } else {
        conv3x3_body<8, 24, 3, 1, 1, 0, 0>(
            lin, blockIdx.x - 1152, 768, p3_pk, wred_pk, x_, nullptr,
            8, 512, 512, 24, 24, nullptr, nullptr);
    }
}

// ---------------------------------------------------------------------------
// MFMA 1x1 conv on packed concat (512->64) + SiLU -> packed bf16 t64.
// ---------------------------------------------------------------------------
__global__ void __launch_bounds__(256)
cat_mfma(const unsigned short* __restrict__ cp_pk, const unsigned short* __restrict__ sp_pk,
         const unsigned short* __restrict__ wpk, unsigned short* __restrict__ outpk) {
    __shared__ __align__(16) unsigned short lin1[128 * 36];
    const int nwg = gridDim.x;
    int wg = (blockIdx.x & 7) * (nwg >> 3) + (blockIdx.x >> 3);
    int mt = wg % 72;
    int b = wg / 72;
    int m0 = mt * 128;
    const int tid = threadIdx.x;
    const int wave = tid >> 6, lane = tid & 63;
    const int l15 = lane & 15, g = lane >> 4;
    const int wpx = wave * 32;

    f32x4 acc[4][2];
#pragma unroll
    for (int af = 0; af < 4; ++af)
#pragma unroll
        for (int bf = 0; bf < 2; ++bf) acc[af][bf] = {};

    for (int ch = 0; ch < 16; ++ch) {
        const unsigned short* src = (ch < 8)
            ? cp_pk + (((size_t)b * 8 + ch) * 9216 + m0) * 32
            : sp_pk + (((size_t)b * 8 + ch - 8) * 9216 + m0) * 32;
#pragma unroll
        for (int it = 0; it < 2; ++it) {
            int e = tid + it * 256;
            int px = e >> 2, cg = e & 3;
            *(uint4*)&lin1[px * 36 + (cg << 3)] = *(const uint4*)&src[px * 32 + (cg << 3)];
        }
        __syncthreads();
        const unsigned short* wb = wpk + ((size_t)ch * 64 + l15) * 32 + g * 8;
        bf16x8 a[4];
#pragma unroll
        for (int af = 0; af < 4; ++af)
            a[af] = *(const bf16x8*)(wb + (af * 16) * 32);
        bf16x8 bb[2];
#pragma unroll
        for (int bf = 0; bf < 2; ++bf)
            bb[bf] = *(const bf16x8*)&lin1[(wpx + bf * 16 + l15) * 36 + g * 8];
#pragma unroll
        for (int af = 0; af < 4; ++af)
#pragma unroll
            for (int bf = 0; bf < 2; ++bf)
                acc[af][bf] = __builtin_amdgcn_mfma_f32_16x16x32_bf16(
                    a[af], bb[bf], acc[af][bf], 0, 0, 0);
        __syncthreads();
    }
#pragma unroll
    for (int af = 0; af < 4; ++af) {
#pragma unroll
        for (int bf = 0; bf < 2; ++bf) {
            int m = m0 + wpx + bf * 16 + l15;
            int o = af * 16 + (g << 2);
            ushort4 s;
            s.x = f2bf(silu_f(acc[af][bf][0]));
            s.y = f2bf(silu_f(acc[af][bf][1]));
            s.z = f2bf(silu_f(acc[af][bf][2]));
            s.w = f2bf(silu_f(acc[af][bf][3]));
            *(ushort4*)&outpk[(((size_t)b * 2 + (o >> 5)) * 9216 + m) * 32 + (o & 31)] = s;
        }
    }
}

// ---------------------------------------------------------------------------
// grid_sample param helper
// ---------------------------------------------------------------------------
DI void gs_params(int x, int y, float ox, float oy, float4* w, int2* p) {
    const float S = 47.5f / 96.f;
    float px = x + ox * S;
    float py = y + oy * S;
    float fx0 = floorf(px), fy0 = floorf(py);
    float wx = px - fx0, wy = py - fy0;
    float vx0 = (fx0 >= 0.f && fx0 <= 95.f) ? 1.f : 0.f;
    float vx1 = (fx0 >= -1.f && fx0 <= 94.f) ? 1.f : 0.f;
    float vy0 = (fy0 >= 0.f && fy0 <= 95.f) ? 1.f : 0.f;
    float vy1 = (fy0 >= -1.f && fy0 <= 94.f) ? 1.f : 0.f;
    int x0 = (int)fminf(fmaxf(fx0, 0.f), 95.f);
    int x1 = (int)fminf(fmaxf(fx0 + 1.f, 0.f), 95.f);
    int y0 = (int)fminf(fmaxf(fy0, 0.f), 95.f);
    int y1 = (int)fminf(fmaxf(fy0 + 1.f, 0.f), 95.f);
    w->x = (1.f - wx) * (1.f - wy) * vx0 * vy0;
    w->y = wx * (1.f - wy) * vx1 * vy0;
    w->z = (1.f - wx) * wy * vx0 * vy1;
    w->w = wx * wy * vx1 * vy1;
    *p = make_int2(x0 | (x1 << 16), y0 | (y1 << 16));
}

// ---------------------------------------------------------------------------
// Direct 3x3 conv (input packed bf16); FUSE 3 = conv + fused grid-sample prep.
// ---------------------------------------------------------------------------
template <int TH, int TW, int CO_BLK, int CO_T, int CIC, int FUSE>
__global__ void __launch_bounds__(576)
conv3x3_kernel(const unsigned short* __restrict__ in, const float* __restrict__ wgt,
               float* __restrict__ out, int B, int Ci, int Co, int H, int W,
               float4* __restrict__ wpar, int2* __restrict__ ipk,
               float2* __restrict__ attp) {
    constexpr int TWH = TW + 2;
    constexpr int TWP = TW + 3;
    constexpr int SPAT = TH * (TW / 4);
    __shared__ float lin[CIC][TH + 2][TWP];
    __shared__ float wls[CIC][9][CO_BLK];
    __shared__ float crs[10][TH * TW + 1];

    const int nTx = W / TW, nTy = H / TH;
    const int nCoG = (Co + CO_BLK - 1) / CO_BLK;
    int bid = blockIdx.x;
    const int cog = bid % nCoG; bid /= nCoG;
    const int tx = bid % nTx;   bid /= nTx;
    const int ty = bid % nTy;
    const int b = bid / nTy;
    const int ox = tx * TW, oy = ty * TH;
    const int co0 = cog * CO_BLK;

    const int tid = threadIdx.x;
    const int cot = tid / SPAT;
    const int sp = tid % SPAT;
    const int r = sp / (TW / 4);
    const int cg = sp % (TW / 4);
    const int nChI = Ci >> 5;

    float acc[4][4];
#pragma unroll
    for (int i = 0; i < 4; ++i)
#pragma unroll
        for (int j = 0; j < 4; ++j) acc[i][j] = 0.f;

    for (int ci0 = 0; ci0 < Ci; ci0 += CIC) {
        for (int e = tid; e < CIC * (TH + 2) * TWH; e += SPAT * CO_T) {
            int xx = e % TWH;
            int yy = (e / TWH) % (TH + 2);
            int cc = e / (TWH * (TH + 2));
            int gy = oy - 1 + yy, gx = ox - 1 + xx;
            float v = 0.f;
            if (gy >= 0 && gy < H && gx >= 0 && gx < W) {
                int ci = ci0 + cc;
                v = bf2f(in[(((size_t)b * nChI + (ci >> 5)) * H * W
                             + (size_t)gy * W + gx) * 32 + (ci & 31)]);
            }
            lin[cc][yy][xx] = v;
        }
        for (int e = tid; e < CIC * 9 * CO_BLK; e += SPAT * CO_T) {
            int col = e % CO_BLK;
            int k = (e / CO_BLK) % 9;
            int cc = e / (CO_BLK * 9);
            int co = co0 + col;
            float v = 0.f;
            if (co < Co) v = wgt[((size_t)co * Ci + ci0 + cc) * 9 + k];
            wls[cc][k][col] = v;
        }
        __syncthreads();
#pragma unroll
        for (int cc = 0; cc < CIC; ++cc) {
            float v0[3][6];
#pragma unroll
            for (int ky = 0; ky < 3; ++ky)
#pragma unroll
                for (int u = 0; u < 6; ++u)
                    v0[ky][u] = lin[cc][r + ky][cg * 4 + u];
#pragma unroll
            for (int ky = 0; ky < 3; ++ky)
#pragma unroll
                for (int kx = 0; kx < 3; ++kx) {
                    const float4 w4 = ld4(&wls[cc][ky * 3 + kx][cot * 4]);
                    const float wv_[4] = {w4.x, w4.y, w4.z, w4.w};
#pragma unroll
                    for (int i = 0; i < 4; ++i)
#pragma unroll
                        for (int j = 0; j < 4; ++j)
                            acc[i][j] = fmaf(wv_[i], v0[ky][kx + j], acc[i][j]);
                }
        }
        __syncthreads();
    }
    if (FUSE == 3) {
#pragma unroll
        for (int i = 0; i < 4; ++i) {
            int co = co0 + cot * 4 + i;
            if (co >= 10) continue;
#pragma unroll
            for (int j = 0; j < 4; ++j)
                crs[co][r * TW + cg * 4 + j] = acc[i][j];
        }
        __syncthreads();
        for (int e = tid; e < TH * TW; e += SPAT * CO_T) {
            int xx = ox + (e % TW), yy = oy + (e / TW);
            int pixg = yy * 96 + xx;
            float4 w; int2 p;
#pragma unroll
            for (int g2 = 0; g2 < 2; ++g2) {
                gs_params(xx, yy, crs[2 * g2][e], crs[2 * g2 + 1][e], &w, &p);
                size_t el = ((size_t)g2 * 8 + b) * 9216 + pixg;
                wpar[el] = w; ipk[el] = p;
                gs_params(xx, yy, crs[4 + 2 * g2][e], crs[5 + 2 * g2][e], &w, &p);
                size_t eh = ((size_t)(2 + g2) * 8 + b) * 9216 + pixg;
                wpar[eh] = w; ipk[eh] = p;
            }
            float2 at;
            at.x = 1.f + tanhf(crs[8][e]);
            at.y = 1.f + tanhf(crs[9][e]);
            attp[(size_t)b * 9216 + pixg] = at;
        }
    } else {
        const int y = oy + r;
        const int xb = ox + cg * 4;
#pragma unroll
        for (int i = 0; i < 4; ++i) {
            int co = co0 + cot * 4 + i;
            if (co >= Co) continue;
            size_t base = (((size_t)b * Co + co) * H + y) * W + xb;
            float4 res;
            res.x = acc[i][0]; res.y = acc[i][1]; res.z = acc[i][2]; res.w = acc[i][3];
            st4(&out[base], res);
        }
    }
}

// ---------------------------------------------------------------------------
// Tiled GEMM. PK=1: write padded packed bf16 (24x24 grid, +2 halo).
// ---------------------------------------------------------------------------
template <int ACT, int PK>
__global__ void __launch_bounds__(256)
gemm_om(const float* __restrict__ W, const float* __restrict__ bias,
        const float* __restrict__ in, float* __restrict__ out,
        unsigned short* __restrict__ pko,
        int B, int C, int O, int M, int nOt, int nMt) {
    __shared__ float xs[32][66];
    __shared__ float wls[64][33];
    int bid = blockIdx.x;
    int mt = bid % nMt; bid /= nMt;
    int ot = bid % nOt;
    int b  = bid / nOt;
    int o0 = ot * 64, m0 = mt * 64;
    int tid = threadIdx.x;
    int m_t = tid & 15, o_g = tid >> 4;
    float acc[4][4];
#pragma unroll
    for (int i = 0; i < 4; ++i)
#pragma unroll
        for (int j = 0; j < 4; ++j) acc[i][j] = 0.f;

    for (int c0 = 0; c0 < C; c0 += 32) {
#pragma unroll
        for (int it = 0; it < 8; ++it) {
            int e = tid + it * 256;
            int mm = e & 63, cc = e >> 6;
            float v = 0.f;
            if (m0 + mm < M) v = in[((size_t)b * C + c0 + cc) * M + m0 + mm];
            xs[cc][mm] = v;
        }
#pragma unroll
        for (int it = 0; it < 8; ++it) {
            int e = tid + it * 256;
            int cc = e & 31, ol = e >> 5;
            float v = 0.f;
            if (o0 + ol < O) v = W[(size_t)(o0 + ol) * C + c0 + cc];
            wls[ol][cc] = v;
        }
        __syncthreads();
#pragma unroll
        for (int cc = 0; cc < 32; ++cc) {
            float xv[4], wv[4];
#pragma unroll
            for (int j = 0; j < 4; ++j) xv[j] = xs[cc][j * 16 + m_t];
#pragma unroll
            for (int i = 0; i < 4; ++i) wv[i] = wls[o_g * 4 + i][cc];
#pragma unroll
            for (int i = 0; i < 4; ++i)
#pragma unroll
                for (int j = 0; j < 4; ++j)
                    acc[i][j] = fmaf(wv[i], xv[j], acc[i][j]);
        }
        __syncthreads();
    }
#pragma unroll
    for (int i = 0; i < 4; ++i) {
        int o = o0 + o_g * 4 + i;
        if (o >= O) continue;
        float bv = bias ? bias[o] : 0.f;
#pragma unroll
        for (int j = 0; j < 4; ++j) {
            int m = m0 + j * 16 + m_t;
            if (m >= M) continue;
            float v = acc[i][j] + bv;
            if (ACT == 1) v = silu_f(v);
            if (PK) {
                int yy = m / 24, xx = m % 24;
                pko[(((size_t)b * (O >> 5) + (o >> 5)) * 676
                     + (size_t)(yy + 1) * 26 + (xx + 1)) * 32 + (o & 31)] = f2bf(v);
            } else {
                out[((size_t)b * O + o) * M + m] = v;
            }
        }
    }
}

// ---------------------------------------------------------------------------
// Merged k/v projection: kv[b][o][50], o<32 -> wk/bk, else wv/bv (o-32).
// ---------------------------------------------------------------------------
__global__ void __launch_bounds__(256)
gemm_kv(const float* __restrict__ wk, const float* __restrict__ bk,
        const float* __restrict__ wv, const float* __restrict__ bv,
        const float* __restrict__ in, float* __restrict__ kv) {
    __shared__ float xs[32][66];
    __shared__ float wls[64][33];
    const int O = 544, M = 50, C = 512;
    int bid = blockIdx.x;
    int ot = bid % 9;
    int b  = bid / 9;
    int o0 = ot * 64;
    int tid = threadIdx.x;
    int m_t = tid & 15, o_g = tid >> 4;
    float acc[4][4];
#pragma unroll
    for (int i = 0; i < 4; ++i)
#pragma unroll
        for (int j = 0; j < 4; ++j) acc[i][j] = 0.f;

    for (int c0 = 0; c0 < C; c0 += 32) {
#pragma unroll
        for (int it = 0; it < 8; ++it) {
            int e = tid + it * 256;
            int mm = e & 63, cc = e >> 6;
            float v = 0.f;
            if (mm < M) v = in[((size_t)b * C + c0 + cc) * M + mm];
            xs[cc][mm] = v;
        }
#pragma unroll
        for (int it = 0; it < 8; ++it) {
            int e = tid + it * 256;
            int cc = e & 31, ol = e >> 5;
            int o = o0 + ol;
            float v = 0.f;
            if (o < 32) v = wk[(size_t)o * C + c0 + cc];
            else if (o < O) v = wv[(size_t)(o - 32) * C + c0 + cc];
            wls[ol][cc] = v;
        }
        __syncthreads();
#pragma unroll
        for (int cc = 0; cc < 32; ++cc) {
            float xv[4], wv_[4];
#pragma unroll
            for (int j = 0; j < 4; ++j) xv[j] = xs[cc][j * 16 + m_t];
#pragma unroll
            for (int i = 0; i < 4; ++i) wv_[i] = wls[o_g * 4 + i][cc];
#pragma unroll
            for (int i = 0; i < 4; ++i)
#pragma unroll
                for (int j = 0; j < 4; ++j)
                    acc[i][j] = fmaf(wv_[i], xv[j], acc[i][j]);
        }
        __syncthreads();
    }
#pragma unroll
    for (int i = 0; i < 4; ++i) {
        int o = o0 + o_g * 4 + i;
        if (o >= O) continue;
        float bvv = (o < 32) ? bk[o] : bv[o - 32];
#pragma unroll
        for (int j = 0; j < 4; ++j) {
            int m = j * 16 + m_t;
            if (m >= M) continue;
            kv[((size_t)b * O + o) * M + m] = acc[i][j] + bvv;
        }
    }
}

// ---------------------------------------------------------------------------
__global__ void psp_kernel(const float* __restrict__ x, float* __restrict__ kf) {
    __shared__ float pl[576];
    int bc = blockIdx.x;
    const float* xp = x + (size_t)bc * 576;
    for (int e = threadIdx.x; e < 576; e += 64) pl[e] = xp[e];
    __syncthreads();
    int m = threadIdx.x;
    if (m < 50) {
        int g, i0;
        if (m < 36)      { g = 6; i0 = m; }
        else if (m < 45) { g = 3; i0 = m - 36; }
        else if (m < 49) { g = 2; i0 = m - 45; }
        else             { g = 1; i0 = 0; }
        int bs = 24 / g;
        int by = i0 / g, bx = i0 % g;
        float s = 0.f;
        for (int yy = 0; yy < bs; ++yy)
            for (int xx = 0; xx < bs; ++xx)
                s += pl[(by * bs + yy) * 24 + bx * bs + xx];
        kf[(size_t)bc * 50 + m] = s / (float)(bs * bs);
    }
}

// ---------------------------------------------------------------------------
// sim = softmax(q^T k); k rows 0..31 of kv[b][544][50]
// ---------------------------------------------------------------------------
__global__ void __launch_bounds__(256)
sim_kernel(const float* __restrict__ q, const float* __restrict__ kv,
           float* __restrict__ simg) {
    __shared__ float qs[32][65];
    __shared__ float ks[32][52];
    __shared__ float sm[64][52];
    int b = blockIdx.x / 9, n0 = (blockIdx.x % 9) * 64;
    int tid = threadIdx.x;
    for (int e = tid; e < 32 * 64; e += 256) {
        int c = e >> 6, n = e & 63;
        qs[c][n] = q[((size_t)b * 32 + c) * 576 + n0 + n];
    }
    for (int e = tid; e < 32 * 50; e += 256) {
        int c = e / 50, m = e % 50;
        ks[c][m] = kv[((size_t)b * 544 + c) * 50 + m];
    }
    __syncthreads();
    for (int e = tid; e < 64 * 50; e += 256) {
        int n = e / 50, m = e % 50;
        float s = 0.f;
#pragma unroll
        for (int c = 0; c < 32; ++c) s = fmaf(qs[c][n], ks[c][m], s);
        sm[n][m] = s;
    }
    __syncthreads();
    if (tid < 64) {
        float mx = -1e30f;
        for (int m = 0; m < 50; ++m) mx = fmaxf(mx, sm[tid][m]);
        float sum = 0.f;
        for (int m = 0; m < 50; ++m) {
            float e2 = __expf(sm[tid][m] - mx);
            sm[tid][m] = e2;
            sum += e2;
        }
        float inv = 1.f / sum;
        for (int m = 0; m < 50; ++m) sm[tid][m] *= inv;
    }
    __syncthreads();
    for (int e = tid; e < 64 * 50; e += 256) {
        int n = e / 50, m = e % 50;
        simg[((size_t)b * 576 + n0 + n) * 50 + m] = sm[n][m];
    }
}

// ---------------------------------------------------------------------------
// ctx[b][c][n] = sum_m v[b][c][m] * sim[b][n][m]; v = kv rows 32..543
// ---------------------------------------------------------------------------
__global__ void __launch_bounds__(256)
ctx_kernel(const float* __restrict__ kv, const float* __restrict__ simg,
           float* __restrict__ ctx) {
    __shared__ float vs[128][54];
    __shared__ float ss[64][54];
    int blk = blockIdx.x;
    int ct = blk & 3; blk >>= 2;
    int nt = blk % 9;
    int b = blk / 9;
    int c0 = ct * 128, n0 = nt * 64;
    int tid = threadIdx.x;
    for (int e = tid; e < 128 * 50; e += 256) {
        int c = e / 50, m = e % 50;
        vs[c][m] = kv[((size_t)b * 544 + 32 + c0 + c) * 50 + m];
    }
    for (int e = tid; e < 64 * 50; e += 256) {
        int n = e / 50, m = e % 50;
        ss[n][m] = simg[((size_t)b * 576 + n0 + n) * 50 + m];
    }
    __syncthreads();
    int n_t = tid & 15;
    int c_t = tid >> 4;
    float acc[8][4];
#pragma unroll
    for (int i = 0; i < 8; ++i)
#pragma unroll
        for (int j = 0; j < 4; ++j) acc[i][j] = 0.f;
    for (int m = 0; m < 50; ++m) {
        float sv[4];
#pragma unroll
        for (int j = 0; j < 4; ++j) sv[j] = ss[j * 16 + n_t][m];
#pragma unroll
        for (int i = 0; i < 8; ++i) {
            float vv = vs[c_t * 8 + i][m];
#pragma unroll
            for (int j = 0; j < 4; ++j) acc[i][j] = fmaf(vv, sv[j], acc[i][j]);
        }
    }
#pragma unroll
    for (int i = 0; i < 8; ++i)
#pragma unroll
        for (int j = 0; j < 4; ++j)
            ctx[((size_t)b * 512 + c0 + c_t * 8 + i) * 576 + n0 + j * 16 + n_t] = acc[i][j];
}

// ---------------------------------------------------------------------------
// Bilinear upsample 24->96 into packed bf16 [b][ch][9216][32]; 8 ci/thread.
// ---------------------------------------------------------------------------
__global__ void upsample2_kernel(const float* __restrict__ in, unsigned short* __restrict__ outpk) {
    int idx = blockIdx.x * 256 + threadIdx.x;
    if (idx >= 8 * 8 * 4 * 9216) return;
    int cg = idx & 3;
    int t = idx >> 2;
    int pix = t % 9216; t /= 9216;
    int ch = t & 7;
    int b = t >> 3;
    int x = pix % 96, y = pix / 96;
    float fy = y * (23.f / 95.f);
    float fx = x * (23.f / 95.f);
    int y0 = (int)fy; if (y0 > 22) y0 = 22;
    int x0 = (int)fx; if (x0 > 22) x0 = 22;
    float wy = fy - y0, wx = fx - x0;
    const float* base = in + ((size_t)b * 256 + ch * 32 + cg * 8) * 576 + y0 * 24 + x0;
    unsigned short s[8];
#pragma unroll
    for (int j = 0; j < 8; ++j) {
        const float* ip = base + (size_t)j * 576;
        float a = ip[0], bb = ip[1], c = ip[24], d = ip[25];
        float l = a * (1.f - wy) + c * wy;
        float r = bb * (1.f - wy) + d * wy;
        s[j] = f2bf(l * (1.f - wx) + r * wx);
    }
    *(uint4*)&outpk[(((size_t)b * 8 + ch) * 9216 + pix) * 32 + cg * 8] =
        make_uint4((unsigned)s[0] | ((unsigned)s[1] << 16),
                   (unsigned)s[2] | ((unsigned)s[3] << 16),
                   (unsigned)s[4] | ((unsigned)s[5] << 16),
                   (unsigned)s[6] | ((unsigned)s[7] << 16));
}

// ---------------------------------------------------------------------------
// grid_sample gather blend from packed bf16: uint4 taps serve 8 channels.
// ---------------------------------------------------------------------------
__global__ void __launch_bounds__(256)
gsample3_kernel(const unsigned short* __restrict__ cp_pk, const unsigned short* __restrict__ sp_pk,
                const float4* __restrict__ wpar, const int2* __restrict__ ipk,
                const float2* __restrict__ attp, float* __restrict__ p5o) {
    int idx = blockIdx.x * 256 + threadIdx.x;
    if (idx >= 8 * 32 * 9216) return;
    int pix = idx % 9216;
    int cb = (idx / 9216) & 31;
    int b = idx / (9216 * 32);
    int c0 = cb * 8;
    int g = c0 >> 7, ch = c0 >> 5, coff = c0 & 31;
    size_t el = ((size_t)g * 8 + b) * 9216 + pix;
    size_t eh = ((size_t)(2 + g) * 8 + b) * 9216 + pix;
    float4 wl = wpar[el]; int2 pl = ipk[el];
    float4 wh = wpar[eh]; int2 ph = ipk[eh];
    float2 at = attp[(size_t)b * 9216 + pix];
    int l00 = (pl.y & 0xffff) * 96 + (pl.x & 0xffff);
    int l01 = (pl.y & 0xffff) * 96 + (pl.x >> 16);
    int l10 = (pl.y >> 16) * 96 + (pl.x & 0xffff);
    int l11 = (pl.y >> 16) * 96 + (pl.x >> 16);
    int h00 = (ph.y & 0xffff) * 96 + (ph.x & 0xffff);
    int h01 = (ph.y & 0xffff) * 96 + (ph.x >> 16);
    int h10 = (ph.y >> 16) * 96 + (ph.x & 0xffff);
    int h11 = (ph.y >> 16) * 96 + (ph.x >> 16);
    const unsigned short* cb0 = cp_pk + (((size_t)b * 8 + ch) * 9216) * 32 + coff;
    const unsigned short* sb0 = sp_pk + (((size_t)b * 8 + ch) * 9216) * 32 + coff;
    ushort4 tc0 = *(const ushort4*)&cb0[(size_t)l00 * 32];
    ushort4 tc0b = *(const ushort4*)&cb0[(size_t)l00 * 32 + 4];
    ushort4 tc1 = *(const ushort4*)&cb0[(size_t)l01 * 32];
    ushort4 tc1b = *(const ushort4*)&cb0[(size_t)l01 * 32 + 4];
    ushort4 tc2 = *(const ushort4*)&cb0[(size_t)l10 * 32];
    ushort4 tc2b = *(const ushort4*)&cb0[(size_t)l10 * 32 + 4];
    ushort4 tc3 = *(const ushort4*)&cb0[(size_t)l11 * 32];
    ushort4 tc3b = *(const ushort4*)&cb0[(size_t)l11 * 32 + 4];
    ushort4 ts0 = *(const ushort4*)&sb0[(size_t)h00 * 32];
    ushort4 ts0b = *(const ushort4*)&sb0[(size_t)h00 * 32 + 4];
    ushort4 ts1 = *(const ushort4*)&sb0[(size_t)h01 * 32];
    ushort4 ts1b = *(const ushort4*)&sb0[(size_t)h01 * 32 + 4];
    ushort4 ts2 = *(const ushort4*)&sb0[(size_t)h10 * 32];
    ushort4 ts2b = *(const ushort4*)&sb0[(size_t)h10 * 32 + 4];
    ushort4 ts3 = *(const ushort4*)&sb0[(size_t)h11 * 32];
    ushort4 ts3b = *(const ushort4*)&sb0[(size_t)h11 * 32 + 4];
    const unsigned short* c0a = (const unsigned short*)&tc0;
    const unsigned short* c0bp = (const unsigned short*)&tc0b;
    const unsigned short* c1a = (const unsigned short*)&tc1;
    const unsigned short* c1bp = (const unsigned short*)&tc1b;
    const unsigned short* c2a = (const unsigned short*)&tc2;
    const unsigned short* c2bp = (const unsigned short*)&tc2b;
    const unsigned short* c3a = (const unsigned short*)&tc3;
    const unsigned short* c3bp = (const unsigned short*)&tc3b;
    const unsigned short* s0a = (const unsigned short*)&ts0;
    const unsigned short* s0bp = (const unsigned short*)&ts0b;
    const unsigned short* s1a = (const unsigned short*)&ts1;
    const unsigned short* s1bp = (const unsigned short*)&ts1b;
    const unsigned short* s2a = (const unsigned short*)&ts2;
    const unsigned short* s2bp = (const unsigned short*)&ts2b;
    const unsigned short* s3a = (const unsigned short*)&ts3;
    const unsigned short* s3bp = (const unsigned short*)&ts3b;
    float* op = p5o + ((size_t)b * 256 + c0) * 9216 + pix;
#pragma unroll
    for (int i = 0; i < 8; ++i) {
        unsigned short v0 = (i < 4) ? c0a[i] : c0bp[i - 4];
        unsigned short v1 = (i < 4) ? c1a[i] : c1bp[i - 4];
        unsigned short v2 = (i < 4) ? c2a[i] : c2bp[i - 4];
        unsigned short v3 = (i < 4) ? c3a[i] : c3bp[i - 4];
        float cps = wl.x * bf2f(v0) + wl.y * bf2f(v1) + wl.z * bf2f(v2) + wl.w * bf2f(v3);
        unsigned short u0 = (i < 4) ? s0a[i] : s0bp[i - 4];
        unsigned short u1 = (i < 4) ? s1a[i] : s1bp[i - 4];
        unsigned short u2 = (i < 4) ? s2a[i] : s2bp[i - 4];
        unsigned short u3 = (i < 4) ? s3a[i] : s3bp[i - 4];
        float sps = wh.x * bf2f(u0) + wh.y * bf2f(u1) + wh.z * bf2f(u2) + wh.w * bf2f(u3);
        op[(size_t)i * 9216] = sps * at.x + cps * at.y;
    }
}

// ---------------------------------------------------------------------------
extern "C" void kernel_launch(void* const* d_in, const int* in_sizes, int n_in,
                              void* d_out, int out_size, void* d_ws, size_t ws_size,
                              hipStream_t stream) {
    const float* p3    = (const float*)d_in[0];
    const float* p5    = (const float*)d_in[1];
    const float* w_red = (const float*)d_in[2];
    const float* wq    = (const float*)d_in[3];
    const float* bq    = (const float*)d_in[4];
    const float* wk    = (const float*)d_in[5];
    const float* bk    = (const float*)d_in[6];
    const float* wv    = (const float*)d_in[7];
    const float* bv    = (const float*)d_in[8];
    const float* la_w1 = (const float*)d_in[9];
    const float* la_w2 = (const float*)d_in[10];
    const float* w32   = (const float*)d_in[11];
    const float* w8    = (const float*)d_in[12];
    const float* woff1 = (const float*)d_in[13];
    const float* woff2 = (const float*)d_in[14];

    float* out = (float*)d_out;
    float* p3o = out;                 // [8,512,24,24]
    float* p5o = out + 2359296;       // [8,256,96,96]

    float* ws = (float*)d_ws;
    float* x_   = ws + 0;
    float* ctx  = ws + 2359296;
    float* q    = ws + 4718592;
    float* kf   = ws + 4866048;
    float* kv   = ws + 5070848;
    unsigned short* la1_pk = (unsigned short*)(ws + 5288448);
    float* sp24 = ws + 5461504;
    float4* wpar = (float4*)(ws + 6641152);
    int2*   ipk  = (int2*)(ws + 7820800);
    float2* attp = (float2*)(ws + 8410624);
    float* simg = ws + 8558080;
    unsigned short* sp96_pk = (unsigned short*)(ws + 8788480);
    unsigned short* cp_pk   = (unsigned short*)(ws + 18225664);
    unsigned short* p5_pk   = (unsigned short*)(ws + 27662848);
    unsigned short* p3_pk   = (unsigned short*)(ws + 37497344);
    unsigned short* wred_pk = (unsigned short*)(ws + 38881792);
    unsigned short* w32_pk  = (unsigned short*)(ws + 40061440);
    unsigned short* w8_pk   = (unsigned short*)(ws + 40651264);
    unsigned short* wla2_pk = (unsigned short*)(ws + 40946176);
    unsigned short* woff1_pk= (unsigned short*)(ws + 41093632);
    unsigned short* t64_pk  = (unsigned short*)(ws + 0);

    // Z0: zero only padded-buffer halo rings
    zero_halo_kernel<<<dim3((64 * 388 + 255) / 256), dim3(256), 0, stream>>>(p5_pk, 64, 98, 98);
    zero_halo_kernel<<<dim3((128 * 100 + 255) / 256), dim3(256), 0, stream>>>(p3_pk, 128, 26, 26);
    zero_halo_kernel<<<dim3((16 * 100 + 255) / 256), dim3(256), 0, stream>>>(la1_pk, 16, 26, 26);

    // P0: weight packs (COG matched to conv WCO)
    pack_w2_kernel<<<dim3(2359296 / 256), dim3(256), 0, stream>>>(w_red, wred_pk, 512, 512, 16);
    pack_w2_kernel<<<dim3(1179648 / 256), dim3(256), 0, stream>>>(w32, w32_pk, 512, 256, 16);
    pack_w2_kernel<<<dim3(589824 / 256), dim3(256), 0, stream>>>(w8, w8_pk, 256, 256, 64);
    pack_w2_kernel<<<dim3(294912 / 256), dim3(256), 0, stream>>>(la_w2, wla2_pk, 64, 512, 16);
    pack_w1_kernel<<<dim3(128), dim3(256), 0, stream>>>(woff1, woff1_pk);
    // P1: padded input packs
    pack_in_pad_kernel<<<dim3(9216), dim3(256), 0, stream>>>(p5, p5_pk, 256, 96, 96, 2359296);
    pack_in_pad_kernel<<<dim3(1152), dim3(256), 0, stream>>>(p3, p3_pk, 512, 24, 24, 294912);

    // K10+K1 fused launch: independent convs co-scheduled (1152 + 768 blocks)
    conv_k10k1<<<dim3(1920), dim3(256), 0, stream>>>(
        p5_pk, w8_pk, cp_pk, p3_pk, wred_pk, x_);
    // K2: q
    gemm_om<0, 0><<<dim3(72), dim3(256), 0, stream>>>(
        wq, bq, x_, q, nullptr, 8, 512, 32, 576, 1, 9);
    // K3: psp
    psp_kernel<<<dim3(8 * 512), dim3(64), 0, stream>>>(x_, kf);
    // K4: merged k+v projection
    gemm_kv<<<dim3(72), dim3(256), 0, stream>>>(wk, bk, wv, bv, kf, kv);
    // K5: attention
    sim_kernel<<<dim3(72), dim3(256), 0, stream>>>(q, kv, simg);
    ctx_kernel<<<dim3(288), dim3(256), 0, stream>>>(kv, simg, ctx);
    // K6: la1 -> padded packed bf16
    gemm_om<1, 1><<<dim3(72), dim3(256), 0, stream>>>(
        la_w1, nullptr, ctx, nullptr, la1_pk, 8, 512, 64, 576, 1, 9);
    // K7: p3o f32 + p3_pk padded packed  [FUSE2, WCO=1]
    conv3x3_mfma3<8, 24, 3, 1, 2, 2, 1><<<dim3(768), dim3(256), 0, stream>>>(
        la1_pk, wla2_pk, p3o, p3_pk, 8, 64, 512, 24, 24, ctx, x_);
    // K8: sp24 = silu(conv3x3(p3o, w32))
    conv3x3_mfma3<8, 24, 3, 1, 1, 0, 0><<<dim3(384), dim3(256), 0, stream>>>(
        p3_pk, w32_pk, sp24, nullptr, 8, 512, 256, 24, 24, nullptr, nullptr);
    // K9: sp96_pk = upsample(sp24)
    upsample2_kernel<<<dim3(9216), dim3(256), 0, stream>>>(sp24, sp96_pk);
    // K11: t64_pk = silu(conv1x1(concat))
    cat_mfma<<<dim3(576), dim3(256), 0, stream>>>(cp_pk, sp96_pk, woff1_pk, t64_pk);
    // K12: conv3x3(t64_pk, woff2) + fused grid-sample prep
    conv3x3_kernel<8, 32, 12, 3, 4, 3><<<dim3(288), dim3(192), 0, stream>>>(
        t64_pk, woff2, nullptr, 8, 64, 10, 96, 96, wpar, ipk, attp);
    // K13: p5o = gather blend
    gsample3_kernel<<<dim3(9216), dim3(256), 0, stream>>>(
        cp_pk, sp96_pk, wpar, ipk, attp, p5o);
}

// Round 17
// 763.077 us; speedup vs baseline: 1.0173x; 1.0173x over previous
//
#include <hip/hip_runtime.h>
#include <math.h>

#define DI __device__ __forceinline__

typedef __attribute__((ext_vector_type(8))) short bf16x8;
typedef __attribute__((ext_vector_type(4))) float f32x4;

DI float silu_f(float v) { return v / (1.f + __expf(-v)); }
DI float4 ld4(const float* p) { return *reinterpret_cast<const float4*>(p); }
DI void st4(float* p, const float4& v) { *reinterpret_cast<float4*>(p) = v; }
DI unsigned short f2bf(float f) {
    unsigned u = __float_as_uint(f);
    unsigned r = (u + 0x7FFFu + ((u >> 16) & 1u)) >> 16;
    return (unsigned short)r;
}
DI float bf2f(unsigned short u) { return __uint_as_float(((unsigned)u) << 16); }

DI void gload_lds16(const unsigned short* g, unsigned short* l) {
    __builtin_amdgcn_global_load_lds(
        (const __attribute__((address_space(1))) void*)g,
        (__attribute__((address_space(3))) void*)l, 16, 0, 0);
}

// ---------------------------------------------------------------------------
// Weight pre-pack v2 (3x3): [Ci/32][Co/COG][9][COG][32]
// ---------------------------------------------------------------------------
__global__ void pack_w2_kernel(const float* __restrict__ w, unsigned short* __restrict__ pk,
                               int Ci, int Co, int COG) {
    int idx = blockIdx.x * 256 + threadIdx.x;
    int total = Ci * Co * 9;
    if (idx >= total) return;
    int cc = idx & 31;
    int t = idx >> 5;
    int col = t % COG; t /= COG;
    int dydx = t % 9;  t /= 9;
    int nCoG = Co / COG;
    int cog = t % nCoG;
    int ch = t / nCoG;
    int co = cog * COG + col;
    pk[idx] = f2bf(w[((size_t)co * Ci + (ch << 5) + cc) * 9 + dydx]);
}

// 1x1 weight pack: w [64][512] -> [16][64][32]
__global__ void pack_w1_kernel(const float* __restrict__ w, unsigned short* __restrict__ pk) {
    int idx = blockIdx.x * 256 + threadIdx.x;
    if (idx >= 32768) return;
    int cc = idx & 31;
    int col = (idx >> 5) & 63;
    int ch = idx >> 11;
    pk[idx] = f2bf(w[(size_t)col * 512 + (ch << 5) + cc]);
}

// ---------------------------------------------------------------------------
// Zero only the 1-px halo ring of a padded packed buffer [P][Hp][Wp][32]
// ---------------------------------------------------------------------------
__global__ void zero_halo_kernel(unsigned short* __restrict__ pk, int P, int Hp, int Wp) {
    int border = 2 * Wp + 2 * (Hp - 2);
    int idx = blockIdx.x * 256 + threadIdx.x;
    if (idx >= P * border) return;
    int i = idx % border;
    int p = idx / border;
    int y, x;
    if (i < Wp) { y = 0; x = i; }
    else if (i < 2 * Wp) { y = Hp - 1; x = i - Wp; }
    else if (i < 2 * Wp + (Hp - 2)) { y = i - 2 * Wp + 1; x = 0; }
    else { y = i - 2 * Wp - (Hp - 2) + 1; x = Wp - 1; }
    unsigned short* d = pk + (((size_t)p * Hp + y) * Wp + x) * 32;
    uint4 z = make_uint4(0, 0, 0, 0);
    *(uint4*)&d[0] = z; *(uint4*)&d[8] = z; *(uint4*)&d[16] = z; *(uint4*)&d[24] = z;
}

// ---------------------------------------------------------------------------
// Input pre-pack with zero halo: f32 NCHW -> bf16 [b][ci/32][H+2][W+2][32]
// ---------------------------------------------------------------------------
__global__ void pack_in_pad_kernel(const float* __restrict__ in, unsigned short* __restrict__ pk,
                                   int Ci, int H, int W, int total) {
    int idx = blockIdx.x * 256 + threadIdx.x;
    if (idx >= total) return;
    const int nCh = Ci >> 5;
    const int HW = H * W;
    int cg = idx & 3;
    int t = idx >> 2;
    int pix = t % HW; t /= HW;
    int ch = t % nCh;
    int b = t / nCh;
    int y = pix / W, x = pix % W;
    const float* src = in + ((size_t)b * Ci + (ch << 5) + (cg << 3)) * HW + pix;
    unsigned p[4];
#pragma unroll
    for (int j = 0; j < 4; ++j) {
        float v0 = src[(size_t)(2 * j) * HW];
        float v1 = src[(size_t)(2 * j + 1) * HW];
        p[j] = (unsigned)f2bf(v0) | ((unsigned)f2bf(v1) << 16);
    }
    size_t dst = (((size_t)b * nCh + ch) * (H + 2) + (y + 1)) * (W + 2) + (x + 1);
    *(uint4*)&pk[dst * 32 + (cg << 3)] = make_uint4(p[0], p[1], p[2], p[3]);
}

// ---------------------------------------------------------------------------
// MFMA implicit-GEMM 3x3 conv, v3b (SETTLED): padded input, global_load_lds
// staging, XOR-swizzled LDS, single buffer, 2 barriers/chunk. Failed variants:
// dbuf (r9,r12), barrier-free (r14), no-LDS (r11), fat-fusion (r16) — all
// regressed via occupancy/VGPR/L2 effects.
// ---------------------------------------------------------------------------
template <int TH, int TW, int BF, int WCO, int FUSE, int OUTPK, int OUTPAD>
__global__ void __launch_bounds__(256)
conv3x3_mfma3(const unsigned short* __restrict__ pin, const unsigned short* __restrict__ wpk,
              float* __restrict__ out, unsigned short* __restrict__ outpk,
              int B, int Ci, int Co, int H, int W,
              const float* __restrict__ ctx, const float* __restrict__ xres) {
    static_assert(TH * TW == 4 * BF * 16, "tile px = 4 waves * BF frags * 16");
    constexpr int COG = WCO * 16;
    constexpr int TWH = TW + 2;
    constexpr int HP = (TH + 2) * TWH;
    constexpr int NG = HP * 4;
    constexpr int NIT = (NG + 255) / 256;
    static_assert(NG % 8 == 0, "granules divisible by 8");
    __shared__ __align__(16) unsigned short lin[NG * 8];

    const int nTx = W / TW, nTy = H / TH, nCoG = Co / COG;
    const int Wp = W + 2, Hp = H + 2;
    const int nwg = gridDim.x;
    int wg = (blockIdx.x & 7) * (nwg >> 3) + (blockIdx.x >> 3);
    const int cog = wg % nCoG; wg /= nCoG;
    const int tx = wg % nTx;   wg /= nTx;
    const int ty = wg % nTy;
    const int b = wg / nTy;
    const int ox = tx * TW, oy = ty * TH, co0 = cog * COG;

    const int tid = threadIdx.x;
    const int lane = tid & 63;
    const int l15 = lane & 15, g = lane >> 4;
    const int wpx = (tid >> 6) * (BF * 16);

    int rr[BF], cc_[BF];
#pragma unroll
    for (int bf = 0; bf < BF; ++bf) {
        int px = wpx + bf * 16 + l15;
        rr[bf] = px / TW;
        cc_[bf] = px % TW;
    }

    f32x4 acc[WCO][BF];
#pragma unroll
    for (int af = 0; af < WCO; ++af)
#pragma unroll
        for (int bf = 0; bf < BF; ++bf) acc[af][bf] = {};

    const int nCh = Ci >> 5;
    const size_t HWs = (size_t)H * W;
    const size_t HpWp = (size_t)Hp * Wp;

    for (int ch = 0; ch < nCh; ++ch) {
        {
            const unsigned short* srcb = pin + ((size_t)b * nCh + ch) * HpWp * 32;
#pragma unroll
            for (int it = 0; it < NIT; ++it) {
                int s = it * 256 + tid;
                if (s < NG) {
                    int e = s ^ ((s >> 3) & 7);
                    int hp = e >> 2, cgp = e & 3;
                    int hy = hp / TWH, hx = hp - hy * TWH;
                    gload_lds16(srcb + ((size_t)(oy + hy) * Wp + (ox + hx)) * 32 + (cgp << 3),
                                &lin[(s & ~63) << 3]);
                }
            }
        }
        __syncthreads();
        {
            const unsigned short* wbase =
                wpk + ((((size_t)ch * nCoG + cog) * 9) * COG + l15) * 32 + (g << 3);
#pragma unroll
            for (int dy = 0; dy < 3; ++dy) {
#pragma unroll
                for (int dx = 0; dx < 3; ++dx) {
                    const int dydx = dy * 3 + dx;
                    bf16x8 a[WCO];
#pragma unroll
                    for (int af = 0; af < WCO; ++af)
                        a[af] = *(const bf16x8*)(wbase + ((size_t)dydx * COG + af * 16) * 32);
                    bf16x8 bb[BF];
#pragma unroll
                    for (int bf = 0; bf < BF; ++bf) {
                        int pxh = (rr[bf] + dy) * TWH + cc_[bf] + dx;
                        int eg = (pxh << 2) | g;
                        int slot = eg ^ ((eg >> 3) & 7);
                        bb[bf] = *(const bf16x8*)&lin[slot << 3];
                    }
#pragma unroll
                    for (int af = 0; af < WCO; ++af)
#pragma unroll
                        for (int bf = 0; bf < BF; ++bf)
                            acc[af][bf] = __builtin_amdgcn_mfma_f32_16x16x32_bf16(
                                a[af], bb[bf], acc[af][bf], 0, 0, 0);
                }
            }
        }
        __syncthreads();
    }

    const int nChO = Co >> 5;
    const size_t opitch = OUTPAD ? (size_t)(H + 2) * (W + 2) : HWs;
#pragma unroll
    for (int af = 0; af < WCO; ++af) {
#pragma unroll
        for (int bf = 0; bf < BF; ++bf) {
            int px = wpx + bf * 16 + l15;
            int y = oy + px / TW, x = ox + px % TW;
            size_t pixg = (size_t)y * W + x;
            int coB = co0 + af * 16 + (g << 2);
            float vv[4];
#pragma unroll
            for (int r4 = 0; r4 < 4; ++r4) {
                float v = acc[af][bf][r4];
                if (FUSE == 1) v = silu_f(v);
                else if (FUSE == 2) {
                    size_t base = ((size_t)b * Co + coB + r4) * HWs + pixg;
                    v = xres[base] + ctx[base] * (1.f + tanhf(v));
                }
                vv[r4] = v;
            }
            if (OUTPK != 1) {
#pragma unroll
                for (int r4 = 0; r4 < 4; ++r4)
                    out[((size_t)b * Co + coB + r4) * HWs + pixg] = vv[r4];
            }
            if (OUTPK >= 1) {
                ushort4 s;
                s.x = f2bf(vv[0]); s.y = f2bf(vv[1]); s.z = f2bf(vv[2]); s.w = f2bf(vv[3]);
                size_t opix = OUTPAD ? ((size_t)(y + 1) * (W + 2) + (x + 1)) : pixg;
                *(ushort4*)&outpk[(((size_t)b * nChO + (coB >> 5)) * opitch + opix) * 32
                                  + (coB & 31)] = s;
            }
        }
    }
}

// ---------------------------------------------------------------------------
// MFMA 1x1 conv on packed concat (512->64) + SiLU -> packed bf16 t64.
// ---------------------------------------------------------------------------
__global__ void __launch_bounds__(256)
cat_mfma(const unsigned short* __restrict__ cp_pk, const unsigned short* __restrict__ sp_pk,
         const unsigned short* __restrict__ wpk, unsigned short* __restrict__ outpk) {
    __shared__ __align__(16) unsigned short lin1[128 * 36];
    const int nwg = gridDim.x;
    int wg = (blockIdx.x & 7) * (nwg >> 3) + (blockIdx.x >> 3);
    int mt = wg % 72;
    int b = wg / 72;
    int m0 = mt * 128;
    const int tid = threadIdx.x;
    const int wave = tid >> 6, lane = tid & 63;
    const int l15 = lane & 15, g = lane >> 4;
    const int wpx = wave * 32;

    f32x4 acc[4][2];
#pragma unroll
    for (int af = 0; af < 4; ++af)
#pragma unroll
        for (int bf = 0; bf < 2; ++bf) acc[af][bf] = {};

    for (int ch = 0; ch < 16; ++ch) {
        const unsigned short* src = (ch < 8)
            ? cp_pk + (((size_t)b * 8 + ch) * 9216 + m0) * 32
            : sp_pk + (((size_t)b * 8 + ch - 8) * 9216 + m0) * 32;
#pragma unroll
        for (int it = 0; it < 2; ++it) {
            int e = tid + it * 256;
            int px = e >> 2, cg = e & 3;
            *(uint4*)&lin1[px * 36 + (cg << 3)] = *(const uint4*)&src[px * 32 + (cg << 3)];
        }
        __syncthreads();
        const unsigned short* wb = wpk + ((size_t)ch * 64 + l15) * 32 + g * 8;
        bf16x8 a[4];
#pragma unroll
        for (int af = 0; af < 4; ++af)
            a[af] = *(const bf16x8*)(wb + (af * 16) * 32);
        bf16x8 bb[2];
#pragma unroll
        for (int bf = 0; bf < 2; ++bf)
            bb[bf] = *(const bf16x8*)&lin1[(wpx + bf * 16 + l15) * 36 + g * 8];
#pragma unroll
        for (int af = 0; af < 4; ++af)
#pragma unroll
            for (int bf = 0; bf < 2; ++bf)
                acc[af][bf] = __builtin_amdgcn_mfma_f32_16x16x32_bf16(
                    a[af], bb[bf], acc[af][bf], 0, 0, 0);
        __syncthreads();
    }
#pragma unroll
    for (int af = 0; af < 4; ++af) {
#pragma unroll
        for (int bf = 0; bf < 2; ++bf) {
            int m = m0 + wpx + bf * 16 + l15;
            int o = af * 16 + (g << 2);
            ushort4 s;
            s.x = f2bf(silu_f(acc[af][bf][0]));
            s.y = f2bf(silu_f(acc[af][bf][1]));
            s.z = f2bf(silu_f(acc[af][bf][2]));
            s.w = f2bf(silu_f(acc[af][bf][3]));
            *(ushort4*)&outpk[(((size_t)b * 2 + (o >> 5)) * 9216 + m) * 32 + (o & 31)] = s;
        }
    }
}

// ---------------------------------------------------------------------------
// grid_sample param helper
// ---------------------------------------------------------------------------
DI void gs_params(int x, int y, float ox, float oy, float4* w, int2* p) {
    const float S = 47.5f / 96.f;
    float px = x + ox * S;
    float py = y + oy * S;
    float fx0 = floorf(px), fy0 = floorf(py);
    float wx = px - fx0, wy = py - fy0;
    float vx0 = (fx0 >= 0.f && fx0 <= 95.f) ? 1.f : 0.f;
    float vx1 = (fx0 >= -1.f && fx0 <= 94.f) ? 1.f : 0.f;
    float vy0 = (fy0 >= 0.f && fy0 <= 95.f) ? 1.f : 0.f;
    float vy1 = (fy0 >= -1.f && fy0 <= 94.f) ? 1.f : 0.f;
    int x0 = (int)fminf(fmaxf(fx0, 0.f), 95.f);
    int x1 = (int)fminf(fmaxf(fx0 + 1.f, 0.f), 95.f);
    int y0 = (int)fminf(fmaxf(fy0, 0.f), 95.f);
    int y1 = (int)fminf(fmaxf(fy0 + 1.f, 0.f), 95.f);
    w->x = (1.f - wx) * (1.f - wy) * vx0 * vy0;
    w->y = wx * (1.f - wy) * vx1 * vy0;
    w->z = (1.f - wx) * wy * vx0 * vy1;
    w->w = wx * wy * vx1 * vy1;
    *p = make_int2(x0 | (x1 << 16), y0 | (y1 << 16));
}

// ---------------------------------------------------------------------------
// Direct 3x3 conv (input packed bf16); FUSE 3 = conv + fused grid-sample prep.
// ---------------------------------------------------------------------------
template <int TH, int TW, int CO_BLK, int CO_T, int CIC, int FUSE>
__global__ void __launch_bounds__(576)
conv3x3_kernel(const unsigned short* __restrict__ in, const float* __restrict__ wgt,
               float* __restrict__ out, int B, int Ci, int Co, int H, int W,
               float4* __restrict__ wpar, int2* __restrict__ ipk,
               float2* __restrict__ attp) {
    constexpr int TWH = TW + 2;
    constexpr int TWP = TW + 3;
    constexpr int SPAT = TH * (TW / 4);
    __shared__ float lin[CIC][TH + 2][TWP];
    __shared__ float wls[CIC][9][CO_BLK];
    __shared__ float crs[10][TH * TW + 1];

    const int nTx = W / TW, nTy = H / TH;
    const int nCoG = (Co + CO_BLK - 1) / CO_BLK;
    int bid = blockIdx.x;
    const int cog = bid % nCoG; bid /= nCoG;
    const int tx = bid % nTx;   bid /= nTx;
    const int ty = bid % nTy;
    const int b = bid / nTy;
    const int ox = tx * TW, oy = ty * TH;
    const int co0 = cog * CO_BLK;

    const int tid = threadIdx.x;
    const int cot = tid / SPAT;
    const int sp = tid % SPAT;
    const int r = sp / (TW / 4);
    const int cg = sp % (TW / 4);
    const int nChI = Ci >> 5;

    float acc[4][4];
#pragma unroll
    for (int i = 0; i < 4; ++i)
#pragma unroll
        for (int j = 0; j < 4; ++j) acc[i][j] = 0.f;

    for (int ci0 = 0; ci0 < Ci; ci0 += CIC) {
        for (int e = tid; e < CIC * (TH + 2) * TWH; e += SPAT * CO_T) {
            int xx = e % TWH;
            int yy = (e / TWH) % (TH + 2);
            int cc = e / (TWH * (TH + 2));
            int gy = oy - 1 + yy, gx = ox - 1 + xx;
            float v = 0.f;
            if (gy >= 0 && gy < H && gx >= 0 && gx < W) {
                int ci = ci0 + cc;
                v = bf2f(in[(((size_t)b * nChI + (ci >> 5)) * H * W
                             + (size_t)gy * W + gx) * 32 + (ci & 31)]);
            }
            lin[cc][yy][xx] = v;
        }
        for (int e = tid; e < CIC * 9 * CO_BLK; e += SPAT * CO_T) {
            int col = e % CO_BLK;
            int k = (e / CO_BLK) % 9;
            int cc = e / (CO_BLK * 9);
            int co = co0 + col;
            float v = 0.f;
            if (co < Co) v = wgt[((size_t)co * Ci + ci0 + cc) * 9 + k];
            wls[cc][k][col] = v;
        }
        __syncthreads();
#pragma unroll
        for (int cc = 0; cc < CIC; ++cc) {
            float v0[3][6];
#pragma unroll
            for (int ky = 0; ky < 3; ++ky)
#pragma unroll
                for (int u = 0; u < 6; ++u)
                    v0[ky][u] = lin[cc][r + ky][cg * 4 + u];
#pragma unroll
            for (int ky = 0; ky < 3; ++ky)
#pragma unroll
                for (int kx = 0; kx < 3; ++kx) {
                    const float4 w4 = ld4(&wls[cc][ky * 3 + kx][cot * 4]);
                    const float wv_[4] = {w4.x, w4.y, w4.z, w4.w};
#pragma unroll
                    for (int i = 0; i < 4; ++i)
#pragma unroll
                        for (int j = 0; j < 4; ++j)
                            acc[i][j] = fmaf(wv_[i], v0[ky][kx + j], acc[i][j]);
                }
        }
        __syncthreads();
    }
    if (FUSE == 3) {
#pragma unroll
        for (int i = 0; i < 4; ++i) {
            int co = co0 + cot * 4 + i;
            if (co >= 10) continue;
#pragma unroll
            for (int j = 0; j < 4; ++j)
                crs[co][r * TW + cg * 4 + j] = acc[i][j];
        }
        __syncthreads();
        for (int e = tid; e < TH * TW; e += SPAT * CO_T) {
            int xx = ox + (e % TW), yy = oy + (e / TW);
            int pixg = yy * 96 + xx;
            float4 w; int2 p;
#pragma unroll
            for (int g2 = 0; g2 < 2; ++g2) {
                gs_params(xx, yy, crs[2 * g2][e], crs[2 * g2 + 1][e], &w, &p);
                size_t el = ((size_t)g2 * 8 + b) * 9216 + pixg;
                wpar[el] = w; ipk[el] = p;
                gs_params(xx, yy, crs[4 + 2 * g2][e], crs[5 + 2 * g2][e], &w, &p);
                size_t eh = ((size_t)(2 + g2) * 8 + b) * 9216 + pixg;
                wpar[eh] = w; ipk[eh] = p;
            }
            float2 at;
            at.x = 1.f + tanhf(crs[8][e]);
            at.y = 1.f + tanhf(crs[9][e]);
            attp[(size_t)b * 9216 + pixg] = at;
        }
    } else {
        const int y = oy + r;
        const int xb = ox + cg * 4;
#pragma unroll
        for (int i = 0; i < 4; ++i) {
            int co = co0 + cot * 4 + i;
            if (co >= Co) continue;
            size_t base = (((size_t)b * Co + co) * H + y) * W + xb;
            float4 res;
            res.x = acc[i][0]; res.y = acc[i][1]; res.z = acc[i][2]; res.w = acc[i][3];
            st4(&out[base], res);
        }
    }
}

// ---------------------------------------------------------------------------
// Tiled GEMM. PK=1: write padded packed bf16 (24x24 grid, +2 halo).
// ---------------------------------------------------------------------------
template <int ACT, int PK>
__global__ void __launch_bounds__(256)
gemm_om(const float* __restrict__ W, const float* __restrict__ bias,
        const float* __restrict__ in, float* __restrict__ out,
        unsigned short* __restrict__ pko,
        int B, int C, int O, int M, int nOt, int nMt) {
    __shared__ float xs[32][66];
    __shared__ float wls[64][33];
    int bid = blockIdx.x;
    int mt = bid % nMt; bid /= nMt;
    int ot = bid % nOt;
    int b  = bid / nOt;
    int o0 = ot * 64, m0 = mt * 64;
    int tid = threadIdx.x;
    int m_t = tid & 15, o_g = tid >> 4;
    float acc[4][4];
#pragma unroll
    for (int i = 0; i < 4; ++i)
#pragma unroll
        for (int j = 0; j < 4; ++j) acc[i][j] = 0.f;

    for (int c0 = 0; c0 < C; c0 += 32) {
#pragma unroll
        for (int it = 0; it < 8; ++it) {
            int e = tid + it * 256;
            int mm = e & 63, cc = e >> 6;
            float v = 0.f;
            if (m0 + mm < M) v = in[((size_t)b * C + c0 + cc) * M + m0 + mm];
            xs[cc][mm] = v;
        }
#pragma unroll
        for (int it = 0; it < 8; ++it) {
            int e = tid + it * 256;
            int cc = e & 31, ol = e >> 5;
            float v = 0.f;
            if (o0 + ol < O) v = W[(size_t)(o0 + ol) * C + c0 + cc];
            wls[ol][cc] = v;
        }
        __syncthreads();
#pragma unroll
        for (int cc = 0; cc < 32; ++cc) {
            float xv[4], wv[4];
#pragma unroll
            for (int j = 0; j < 4; ++j) xv[j] = xs[cc][j * 16 + m_t];
#pragma unroll
            for (int i = 0; i < 4; ++i) wv[i] = wls[o_g * 4 + i][cc];
#pragma unroll
            for (int i = 0; i < 4; ++i)
#pragma unroll
                for (int j = 0; j < 4; ++j)
                    acc[i][j] = fmaf(wv[i], xv[j], acc[i][j]);
        }
        __syncthreads();
    }
#pragma unroll
    for (int i = 0; i < 4; ++i) {
        int o = o0 + o_g * 4 + i;
        if (o >= O) continue;
        float bv = bias ? bias[o] : 0.f;
#pragma unroll
        for (int j = 0; j < 4; ++j) {
            int m = m0 + j * 16 + m_t;
            if (m >= M) continue;
            float v = acc[i][j] + bv;
            if (ACT == 1) v = silu_f(v);
            if (PK) {
                int yy = m / 24, xx = m % 24;
                pko[(((size_t)b * (O >> 5) + (o >> 5)) * 676
                     + (size_t)(yy + 1) * 26 + (xx + 1)) * 32 + (o & 31)] = f2bf(v);
            } else {
                out[((size_t)b * O + o) * M + m] = v;
            }
        }
    }
}

// ---------------------------------------------------------------------------
// Merged k/v projection: kv[b][o][50], o<32 -> wk/bk, else wv/bv (o-32).
// ---------------------------------------------------------------------------
__global__ void __launch_bounds__(256)
gemm_kv(const float* __restrict__ wk, const float* __restrict__ bk,
        const float* __restrict__ wv, const float* __restrict__ bv,
        const float* __restrict__ in, float* __restrict__ kv) {
    __shared__ float xs[32][66];
    __shared__ float wls[64][33];
    const int O = 544, M = 50, C = 512;
    int bid = blockIdx.x;
    int ot = bid % 9;
    int b  = bid / 9;
    int o0 = ot * 64;
    int tid = threadIdx.x;
    int m_t = tid & 15, o_g = tid >> 4;
    float acc[4][4];
#pragma unroll
    for (int i = 0; i < 4; ++i)
#pragma unroll
        for (int j = 0; j < 4; ++j) acc[i][j] = 0.f;

    for (int c0 = 0; c0 < C; c0 += 32) {
#pragma unroll
        for (int it = 0; it < 8; ++it) {
            int e = tid + it * 256;
            int mm = e & 63, cc = e >> 6;
            float v = 0.f;
            if (mm < M) v = in[((size_t)b * C + c0 + cc) * M + mm];
            xs[cc][mm] = v;
        }
#pragma unroll
        for (int it = 0; it < 8; ++it) {
            int e = tid + it * 256;
            int cc = e & 31, ol = e >> 5;
            int o = o0 + ol;
            float v = 0.f;
            if (o < 32) v = wk[(size_t)o * C + c0 + cc];
            else if (o < O) v = wv[(size_t)(o - 32) * C + c0 + cc];
            wls[ol][cc] = v;
        }
        __syncthreads();
#pragma unroll
        for (int cc = 0; cc < 32; ++cc) {
            float xv[4], wv_[4];
#pragma unroll
            for (int j = 0; j < 4; ++j) xv[j] = xs[cc][j * 16 + m_t];
#pragma unroll
            for (int i = 0; i < 4; ++i) wv_[i] = wls[o_g * 4 + i][cc];
#pragma unroll
            for (int i = 0; i < 4; ++i)
#pragma unroll
                for (int j = 0; j < 4; ++j)
                    acc[i][j] = fmaf(wv_[i], xv[j], acc[i][j]);
        }
        __syncthreads();
    }
#pragma unroll
    for (int i = 0; i < 4; ++i) {
        int o = o0 + o_g * 4 + i;
        if (o >= O) continue;
        float bvv = (o < 32) ? bk[o] : bv[o - 32];
#pragma unroll
        for (int j = 0; j < 4; ++j) {
            int m = j * 16 + m_t;
            if (m >= M) continue;
            kv[((size_t)b * O + o) * M + m] = acc[i][j] + bvv;
        }
    }
}

// ---------------------------------------------------------------------------
__global__ void psp_kernel(const float* __restrict__ x, float* __restrict__ kf) {
    __shared__ float pl[576];
    int bc = blockIdx.x;
    const float* xp = x + (size_t)bc * 576;
    for (int e = threadIdx.x; e < 576; e += 64) pl[e] = xp[e];
    __syncthreads();
    int m = threadIdx.x;
    if (m < 50) {
        int g, i0;
        if (m < 36)      { g = 6; i0 = m; }
        else if (m < 45) { g = 3; i0 = m - 36; }
        else if (m < 49) { g = 2; i0 = m - 45; }
        else             { g = 1; i0 = 0; }
        int bs = 24 / g;
        int by = i0 / g, bx = i0 % g;
        float s = 0.f;
        for (int yy = 0; yy < bs; ++yy)
            for (int xx = 0; xx < bs; ++xx)
                s += pl[(by * bs + yy) * 24 + bx * bs + xx];
        kf[(size_t)bc * 50 + m] = s / (float)(bs * bs);
    }
}

// ---------------------------------------------------------------------------
// sim = softmax(q^T k); k rows 0..31 of kv[b][544][50]
// ---------------------------------------------------------------------------
__global__ void __launch_bounds__(256)
sim_kernel(const float* __restrict__ q, const float* __restrict__ kv,
           float* __restrict__ simg) {
    __shared__ float qs[32][65];
    __shared__ float ks[32][52];
    __shared__ float sm[64][52];
    int b = blockIdx.x / 9, n0 = (blockIdx.x % 9) * 64;
    int tid = threadIdx.x;
    for (int e = tid; e < 32 * 64; e += 256) {
        int c = e >> 6, n = e & 63;
        qs[c][n] = q[((size_t)b * 32 + c) * 576 + n0 + n];
    }
    for (int e = tid; e < 32 * 50; e += 256) {
        int c = e / 50, m = e % 50;
        ks[c][m] = kv[((size_t)b * 544 + c) * 50 + m];
    }
    __syncthreads();
    for (int e = tid; e < 64 * 50; e += 256) {
        int n = e / 50, m = e % 50;
        float s = 0.f;
#pragma unroll
        for (int c = 0; c < 32; ++c) s = fmaf(qs[c][n], ks[c][m], s);
        sm[n][m] = s;
    }
    __syncthreads();
    if (tid < 64) {
        float mx = -1e30f;
        for (int m = 0; m < 50; ++m) mx = fmaxf(mx, sm[tid][m]);
        float sum = 0.f;
        for (int m = 0; m < 50; ++m) {
            float e2 = __expf(sm[tid][m] - mx);
            sm[tid][m] = e2;
            sum += e2;
        }
        float inv = 1.f / sum;
        for (int m = 0; m < 50; ++m) sm[tid][m] *= inv;
    }
    __syncthreads();
    for (int e = tid; e < 64 * 50; e += 256) {
        int n = e / 50, m = e % 50;
        simg[((size_t)b * 576 + n0 + n) * 50 + m] = sm[n][m];
    }
}

// ---------------------------------------------------------------------------
// ctx[b][c][n] = sum_m v[b][c][m] * sim[b][n][m]; v = kv rows 32..543
// ---------------------------------------------------------------------------
__global__ void __launch_bounds__(256)
ctx_kernel(const float* __restrict__ kv, const float* __restrict__ simg,
           float* __restrict__ ctx) {
    __shared__ float vs[128][54];
    __shared__ float ss[64][54];
    int blk = blockIdx.x;
    int ct = blk & 3; blk >>= 2;
    int nt = blk % 9;
    int b = blk / 9;
    int c0 = ct * 128, n0 = nt * 64;
    int tid = threadIdx.x;
    for (int e = tid; e < 128 * 50; e += 256) {
        int c = e / 50, m = e % 50;
        vs[c][m] = kv[((size_t)b * 544 + 32 + c0 + c) * 50 + m];
    }
    for (int e = tid; e < 64 * 50; e += 256) {
        int n = e / 50, m = e % 50;
        ss[n][m] = simg[((size_t)b * 576 + n0 + n) * 50 + m];
    }
    __syncthreads();
    int n_t = tid & 15;
    int c_t = tid >> 4;
    float acc[8][4];
#pragma unroll
    for (int i = 0; i < 8; ++i)
#pragma unroll
        for (int j = 0; j < 4; ++j) acc[i][j] = 0.f;
    for (int m = 0; m < 50; ++m) {
        float sv[4];
#pragma unroll
        for (int j = 0; j < 4; ++j) sv[j] = ss[j * 16 + n_t][m];
#pragma unroll
        for (int i = 0; i < 8; ++i) {
            float vv = vs[c_t * 8 + i][m];
#pragma unroll
            for (int j = 0; j < 4; ++j) acc[i][j] = fmaf(vv, sv[j], acc[i][j]);
        }
    }
#pragma unroll
    for (int i = 0; i < 8; ++i)
#pragma unroll
        for (int j = 0; j < 4; ++j)
            ctx[((size_t)b * 512 + c0 + c_t * 8 + i) * 576 + n0 + j * 16 + n_t] = acc[i][j];
}

// ---------------------------------------------------------------------------
// Bilinear upsample 24->96 into packed bf16 [b][ch][9216][32]; 8 ci/thread.
// ---------------------------------------------------------------------------
__global__ void upsample2_kernel(const float* __restrict__ in, unsigned short* __restrict__ outpk) {
    int idx = blockIdx.x * 256 + threadIdx.x;
    if (idx >= 8 * 8 * 4 * 9216) return;
    int cg = idx & 3;
    int t = idx >> 2;
    int pix = t % 9216; t /= 9216;
    int ch = t & 7;
    int b = t >> 3;
    int x = pix % 96, y = pix / 96;
    float fy = y * (23.f / 95.f);
    float fx = x * (23.f / 95.f);
    int y0 = (int)fy; if (y0 > 22) y0 = 22;
    int x0 = (int)fx; if (x0 > 22) x0 = 22;
    float wy = fy - y0, wx = fx - x0;
    const float* base = in + ((size_t)b * 256 + ch * 32 + cg * 8) * 576 + y0 * 24 + x0;
    unsigned short s[8];
#pragma unroll
    for (int j = 0; j < 8; ++j) {
        const float* ip = base + (size_t)j * 576;
        float a = ip[0], bb = ip[1], c = ip[24], d = ip[25];
        float l = a * (1.f - wy) + c * wy;
        float r = bb * (1.f - wy) + d * wy;
        s[j] = f2bf(l * (1.f - wx) + r * wx);
    }
    *(uint4*)&outpk[(((size_t)b * 8 + ch) * 9216 + pix) * 32 + cg * 8] =
        make_uint4((unsigned)s[0] | ((unsigned)s[1] << 16),
                   (unsigned)s[2] | ((unsigned)s[3] << 16),
                   (unsigned)s[4] | ((unsigned)s[5] << 16),
                   (unsigned)s[6] | ((unsigned)s[7] << 16));
}

// ---------------------------------------------------------------------------
// grid_sample gather blend from packed bf16: uint4 taps serve 8 channels.
// ---------------------------------------------------------------------------
__global__ void __launch_bounds__(256)
gsample3_kernel(const unsigned short* __restrict__ cp_pk, const unsigned short* __restrict__ sp_pk,
                const float4* __restrict__ wpar, const int2* __restrict__ ipk,
                const float2* __restrict__ attp, float* __restrict__ p5o) {
    int idx = blockIdx.x * 256 + threadIdx.x;
    if (idx >= 8 * 32 * 9216) return;
    int pix = idx % 9216;
    int cb = (idx / 9216) & 31;
    int b = idx / (9216 * 32);
    int c0 = cb * 8;
    int g = c0 >> 7, ch = c0 >> 5, coff = c0 & 31;
    size_t el = ((size_t)g * 8 + b) * 9216 + pix;
    size_t eh = ((size_t)(2 + g) * 8 + b) * 9216 + pix;
    float4 wl = wpar[el]; int2 pl = ipk[el];
    float4 wh = wpar[eh]; int2 ph = ipk[eh];
    float2 at = attp[(size_t)b * 9216 + pix];
    int l00 = (pl.y & 0xffff) * 96 + (pl.x & 0xffff);
    int l01 = (pl.y & 0xffff) * 96 + (pl.x >> 16);
    int l10 = (pl.y >> 16) * 96 + (pl.x & 0xffff);
    int l11 = (pl.y >> 16) * 96 + (pl.x >> 16);
    int h00 = (ph.y & 0xffff) * 96 + (ph.x & 0xffff);
    int h01 = (ph.y & 0xffff) * 96 + (ph.x >> 16);
    int h10 = (ph.y >> 16) * 96 + (ph.x & 0xffff);
    int h11 = (ph.y >> 16) * 96 + (ph.x >> 16);
    const unsigned short* cb0 = cp_pk + (((size_t)b * 8 + ch) * 9216) * 32 + coff;
    const unsigned short* sb0 = sp_pk + (((size_t)b * 8 + ch) * 9216) * 32 + coff;
    ushort4 tc0 = *(const ushort4*)&cb0[(size_t)l00 * 32];
    ushort4 tc0b = *(const ushort4*)&cb0[(size_t)l00 * 32 + 4];
    ushort4 tc1 = *(const ushort4*)&cb0[(size_t)l01 * 32];
    ushort4 tc1b = *(const ushort4*)&cb0[(size_t)l01 * 32 + 4];
    ushort4 tc2 = *(const ushort4*)&cb0[(size_t)l10 * 32];
    ushort4 tc2b = *(const ushort4*)&cb0[(size_t)l10 * 32 + 4];
    ushort4 tc3 = *(const ushort4*)&cb0[(size_t)l11 * 32];
    ushort4 tc3b = *(const ushort4*)&cb0[(size_t)l11 * 32 + 4];
    ushort4 ts0 = *(const ushort4*)&sb0[(size_t)h00 * 32];
    ushort4 ts0b = *(const ushort4*)&sb0[(size_t)h00 * 32 + 4];
    ushort4 ts1 = *(const ushort4*)&sb0[(size_t)h01 * 32];
    ushort4 ts1b = *(const ushort4*)&sb0[(size_t)h01 * 32 + 4];
    ushort4 ts2 = *(const ushort4*)&sb0[(size_t)h10 * 32];
    ushort4 ts2b = *(const ushort4*)&sb0[(size_t)h10 * 32 + 4];
    ushort4 ts3 = *(const ushort4*)&sb0[(size_t)h11 * 32];
    ushort4 ts3b = *(const ushort4*)&sb0[(size_t)h11 * 32 + 4];
    const unsigned short* c0a = (const unsigned short*)&tc0;
    const unsigned short* c0bp = (const unsigned short*)&tc0b;
    const unsigned short* c1a = (const unsigned short*)&tc1;
    const unsigned short* c1bp = (const unsigned short*)&tc1b;
    const unsigned short* c2a = (const unsigned short*)&tc2;
    const unsigned short* c2bp = (const unsigned short*)&tc2b;
    const unsigned short* c3a = (const unsigned short*)&tc3;
    const unsigned short* c3bp = (const unsigned short*)&tc3b;
    const unsigned short* s0a = (const unsigned short*)&ts0;
    const unsigned short* s0bp = (const unsigned short*)&ts0b;
    const unsigned short* s1a = (const unsigned short*)&ts1;
    const unsigned short* s1bp = (const unsigned short*)&ts1b;
    const unsigned short* s2a = (const unsigned short*)&ts2;
    const unsigned short* s2bp = (const unsigned short*)&ts2b;
    const unsigned short* s3a = (const unsigned short*)&ts3;
    const unsigned short* s3bp = (const unsigned short*)&ts3b;
    float* op = p5o + ((size_t)b * 256 + c0) * 9216 + pix;
#pragma unroll
    for (int i = 0; i < 8; ++i) {
        unsigned short v0 = (i < 4) ? c0a[i] : c0bp[i - 4];
        unsigned short v1 = (i < 4) ? c1a[i] : c1bp[i - 4];
        unsigned short v2 = (i < 4) ? c2a[i] : c2bp[i - 4];
        unsigned short v3 = (i < 4) ? c3a[i] : c3bp[i - 4];
        float cps = wl.x * bf2f(v0) + wl.y * bf2f(v1) + wl.z * bf2f(v2) + wl.w * bf2f(v3);
        unsigned short u0 = (i < 4) ? s0a[i] : s0bp[i - 4];
        unsigned short u1 = (i < 4) ? s1a[i] : s1bp[i - 4];
        unsigned short u2 = (i < 4) ? s2a[i] : s2bp[i - 4];
        unsigned short u3 = (i < 4) ? s3a[i] : s3bp[i - 4];
        float sps = wh.x * bf2f(u0) + wh.y * bf2f(u1) + wh.z * bf2f(u2) + wh.w * bf2f(u3);
        op[(size_t)i * 9216] = sps * at.x + cps * at.y;
    }
}

// ---------------------------------------------------------------------------
extern "C" void kernel_launch(void* const* d_in, const int* in_sizes, int n_in,
                              void* d_out, int out_size, void* d_ws, size_t ws_size,
                              hipStream_t stream) {
    const float* p3    = (const float*)d_in[0];
    const float* p5    = (const float*)d_in[1];
    const float* w_red = (const float*)d_in[2];
    const float* wq    = (const float*)d_in[3];
    const float* bq    = (const float*)d_in[4];
    const float* wk    = (const float*)d_in[5];
    const float* bk    = (const float*)d_in[6];
    const float* wv    = (const float*)d_in[7];
    const float* bv    = (const float*)d_in[8];
    const float* la_w1 = (const float*)d_in[9];
    const float* la_w2 = (const float*)d_in[10];
    const float* w32   = (const float*)d_in[11];
    const float* w8    = (const float*)d_in[12];
    const float* woff1 = (const float*)d_in[13];
    const float* woff2 = (const float*)d_in[14];

    float* out = (float*)d_out;
    float* p3o = out;                 // [8,512,24,24]
    float* p5o = out + 2359296;       // [8,256,96,96]

    float* ws = (float*)d_ws;
    float* x_   = ws + 0;
    float* ctx  = ws + 2359296;
    float* q    = ws + 4718592;
    float* kf   = ws + 4866048;
    float* kv   = ws + 5070848;
    unsigned short* la1_pk = (unsigned short*)(ws + 5288448);
    float* sp24 = ws + 5461504;
    float4* wpar = (float4*)(ws + 6641152);
    int2*   ipk  = (int2*)(ws + 7820800);
    float2* attp = (float2*)(ws + 8410624);
    float* simg = ws + 8558080;
    unsigned short* sp96_pk = (unsigned short*)(ws + 8788480);
    unsigned short* cp_pk   = (unsigned short*)(ws + 18225664);
    unsigned short* p5_pk   = (unsigned short*)(ws + 27662848);
    unsigned short* p3_pk   = (unsigned short*)(ws + 37497344);
    unsigned short* wred_pk = (unsigned short*)(ws + 38881792);
    unsigned short* w32_pk  = (unsigned short*)(ws + 40061440);
    unsigned short* w8_pk   = (unsigned short*)(ws + 40651264);
    unsigned short* wla2_pk = (unsigned short*)(ws + 40946176);
    unsigned short* woff1_pk= (unsigned short*)(ws + 41093632);
    unsigned short* t64_pk  = (unsigned short*)(ws + 0);

    // Z0: zero only padded-buffer halo rings
    zero_halo_kernel<<<dim3((64 * 388 + 255) / 256), dim3(256), 0, stream>>>(p5_pk, 64, 98, 98);
    zero_halo_kernel<<<dim3((128 * 100 + 255) / 256), dim3(256), 0, stream>>>(p3_pk, 128, 26, 26);
    zero_halo_kernel<<<dim3((16 * 100 + 255) / 256), dim3(256), 0, stream>>>(la1_pk, 16, 26, 26);

    // P0: weight packs (COG matched to conv WCO)
    pack_w2_kernel<<<dim3(2359296 / 256), dim3(256), 0, stream>>>(w_red, wred_pk, 512, 512, 16);
    pack_w2_kernel<<<dim3(1179648 / 256), dim3(256), 0, stream>>>(w32, w32_pk, 512, 256, 16);
    pack_w2_kernel<<<dim3(589824 / 256), dim3(256), 0, stream>>>(w8, w8_pk, 256, 256, 64);
    pack_w2_kernel<<<dim3(294912 / 256), dim3(256), 0, stream>>>(la_w2, wla2_pk, 64, 512, 16);
    pack_w1_kernel<<<dim3(128), dim3(256), 0, stream>>>(woff1, woff1_pk);
    // P1: padded input packs
    pack_in_pad_kernel<<<dim3(9216), dim3(256), 0, stream>>>(p5, p5_pk, 256, 96, 96, 2359296);
    pack_in_pad_kernel<<<dim3(1152), dim3(256), 0, stream>>>(p3, p3_pk, 512, 24, 24, 294912);

    // K10: cp_pk = silu(conv3x3(p5, w8))  [v3b, proven 120us]
    conv3x3_mfma3<16, 16, 4, 4, 1, 1, 0><<<dim3(1152), dim3(256), 0, stream>>>(
        p5_pk, w8_pk, nullptr, cp_pk, 8, 256, 256, 96, 96, nullptr, nullptr);
    // K1: x = silu(conv3x3(p3, w_red))  [WCO=1, grid 768]
    conv3x3_mfma3<8, 24, 3, 1, 1, 0, 0><<<dim3(768), dim3(256), 0, stream>>>(
        p3_pk, wred_pk, x_, nullptr, 8, 512, 512, 24, 24, nullptr, nullptr);
    // K2: q
    gemm_om<0, 0><<<dim3(72), dim3(256), 0, stream>>>(
        wq, bq, x_, q, nullptr, 8, 512, 32, 576, 1, 9);
    // K3: psp
    psp_kernel<<<dim3(8 * 512), dim3(64), 0, stream>>>(x_, kf);
    // K4: merged k+v projection
    gemm_kv<<<dim3(72), dim3(256), 0, stream>>>(wk, bk, wv, bv, kf, kv);
    // K5: attention
    sim_kernel<<<dim3(72), dim3(256), 0, stream>>>(q, kv, simg);
    ctx_kernel<<<dim3(288), dim3(256), 0, stream>>>(kv, simg, ctx);
    // K6: la1 -> padded packed bf16
    gemm_om<1, 1><<<dim3(72), dim3(256), 0, stream>>>(
        la_w1, nullptr, ctx, nullptr, la1_pk, 8, 512, 64, 576, 1, 9);
    // K7: p3o f32 + p3_pk padded packed  [FUSE2, WCO=1]
    conv3x3_mfma3<8, 24, 3, 1, 2, 2, 1><<<dim3(768), dim3(256), 0, stream>>>(
        la1_pk, wla2_pk, p3o, p3_pk, 8, 64, 512, 24, 24, ctx, x_);
    // K8: sp24 = silu(conv3x3(p3o, w32))
    conv3x3_mfma3<8, 24, 3, 1, 1, 0, 0><<<dim3(384), dim3(256), 0, stream>>>(
        p3_pk, w32_pk, sp24, nullptr, 8, 512, 256, 24, 24, nullptr, nullptr);
    // K9: sp96_pk = upsample(sp24)
    upsample2_kernel<<<dim3(9216), dim3(256), 0, stream>>>(sp24, sp96_pk);
    // K11: t64_pk = silu(conv1x1(concat))
    cat_mfma<<<dim3(576), dim3(256), 0, stream>>>(cp_pk, sp96_pk, woff1_pk, t64_pk);
    // K12: conv3x3(t64_pk, woff2) + fused grid-sample prep
    conv3x3_kernel<8, 32, 12, 3, 4, 3><<<dim3(288), dim3(192), 0, stream>>>(
        t64_pk, woff2, nullptr, 8, 64, 10, 96, 96, wpar, ipk, attp);
    // K13: p5o = gather blend
    gsample3_kernel<<<dim3(9216), dim3(256), 0, stream>>>(
        cp_pk, sp96_pk, wpar, ipk, attp, p5o);
}